// Round 5
// baseline (4960.697 us; speedup 1.0000x reference)
//
#include <hip/hip_runtime.h>
#include <stdint.h>

#define BATCH 32
#define NV    10242
#define NF    20480
#define NBB   64          // 2 hemis * 32 batches ; lane = bb
#define NSTEPS 10
#define STEPSZ 0.1f
#define EPSV   1e-8f

#define VPW    2                          // vertices per wave (R3: 4 spilled; 2 is the knee)
#define VPB    8                          // vertices per block (4 waves * VPW)
#define GROUPS ((NV + VPB - 1) / VPB)     // 1281
#define GPC    ((GROUPS + 7) / 8)         // 161 groups per XCD chunk
#define NBLK   (GPC * 8)                  // 1288 blocks

// ---------------- workspace layout (all state transposed to [V][ch][NBB]) ----------------
static constexpr size_t OFF_V    = 0;                               // [V][3][NBB]  f32
static constexpr size_t OFF_SULC = OFF_V    + (size_t)NV * 3 * NBB; // [V][NBB]     f32
static constexpr size_t OFF_FEAT = OFF_SULC + (size_t)NV * NBB;     // [V][9][NBB]  f32 (v,n,lap)
static constexpr size_t OFF_H    = OFF_FEAT + (size_t)NV * 9 * NBB; // [V][16][NBB] f32
static constexpr size_t OFF_CSZ  = OFF_H    + (size_t)NV * 16 * NBB;// [6][NBB]
static constexpr size_t OFF_INT  = OFF_CSZ  + 6 * NBB;
// int region: deg[NV], nbrB[NV*6] (ring-sorted after k_sortring), nbrC[NV*6]

__device__ __forceinline__ int rfl(int x) { return __builtin_amdgcn_readfirstlane(x); }
// XCD swizzle: chunk = blockIdx%8 owns contiguous GPC groups -> contiguous vertex range per XCD L2
__device__ __forceinline__ int swiz(int b) { return (b & 7) * GPC + (b >> 3); }

// ---------------- adjacency build ----------------
__global__ __launch_bounds__(256) void k_zero_deg(int* deg) {
    int i = blockIdx.x * 256 + threadIdx.x;
    if (i < NV) deg[i] = 0;
}

__global__ __launch_bounds__(256) void k_build(const int* __restrict__ faces,
                                               int* deg, int* nbrB, int* nbrC) {
    int fi = blockIdx.x * 256 + threadIdx.x;
    if (fi >= NF) return;
    int vv[3] = {faces[fi * 3 + 0], faces[fi * 3 + 1], faces[fi * 3 + 2]};
#pragma unroll
    for (int c = 0; c < 3; c++) {
        int vtx = vv[c];
        int s = atomicAdd(&deg[vtx], 1);
        nbrB[vtx * 6 + s] = vv[(c + 1) % 3];   // next corner (dedup'd neighbor)
        nbrC[vtx * 6 + s] = vv[(c + 2) % 3];   // prev corner
    }
}

// sort each 1-ring so that C_t == B_{t+1}: consecutive ring entries form each face's (B,C)
__global__ __launch_bounds__(256) void k_sortring(const int* __restrict__ deg,
                                                  int* nbrB, const int* __restrict__ nbrC) {
    int vi = blockIdx.x * 256 + threadIdx.x;
    if (vi >= NV) return;
    int d = deg[vi];
    int b[6], c[6];
#pragma unroll
    for (int k = 0; k < 6; k++) {
        b[k] = (k < d) ? nbrB[vi * 6 + k] : -1;
        c[k] = (k < d) ? nbrC[vi * 6 + k] : -2;
    }
    int ord[6];
    ord[0] = b[0];
    int cur = c[0];
#pragma unroll
    for (int t = 1; t < 6; t++) {
        int nxt = cur, nc = cur;
#pragma unroll
        for (int k = 0; k < 6; k++)
            if (b[k] == cur) { nxt = b[k]; nc = c[k]; }
        ord[t] = nxt;
        cur = nc;
    }
#pragma unroll
    for (int t = 0; t < 6; t++)
        if (t < d) nbrB[vi * 6 + t] = ord[t];
}

// ---------------- bbox + normalize + transpose-in (one block per bb) ----------------
__global__ __launch_bounds__(256) void k_norm(const float* __restrict__ lh,
                                              const float* __restrict__ rh,
                                              float* __restrict__ v,
                                              float* __restrict__ sulc,
                                              float* __restrict__ csz) {
    int bb = blockIdx.x;
    const float* src = (bb < BATCH) ? (lh + (size_t)bb * NV * 3)
                                    : (rh + (size_t)(bb - BATCH) * NV * 3);
    __shared__ float smin[3][256], smax[3][256];
    float mn[3] = {1e30f, 1e30f, 1e30f}, mx[3] = {-1e30f, -1e30f, -1e30f};
    for (int i = threadIdx.x; i < NV; i += 256) {
#pragma unroll
        for (int c = 0; c < 3; c++) {
            float x = src[i * 3 + c];
            mn[c] = fminf(mn[c], x);
            mx[c] = fmaxf(mx[c], x);
        }
    }
#pragma unroll
    for (int c = 0; c < 3; c++) { smin[c][threadIdx.x] = mn[c]; smax[c][threadIdx.x] = mx[c]; }
    __syncthreads();
    for (int s = 128; s > 0; s >>= 1) {
        if (threadIdx.x < s) {
#pragma unroll
            for (int c = 0; c < 3; c++) {
                smin[c][threadIdx.x] = fminf(smin[c][threadIdx.x], smin[c][threadIdx.x + s]);
                smax[c][threadIdx.x] = fmaxf(smax[c][threadIdx.x], smax[c][threadIdx.x + s]);
            }
        }
        __syncthreads();
    }
    float ctr[3], sz[3];
#pragma unroll
    for (int c = 0; c < 3; c++) {
        ctr[c] = 0.5f * (smin[c][0] + smax[c][0]);
        sz[c]  = smax[c][0] - ctr[c];
    }
    if (threadIdx.x == 0) {
#pragma unroll
        for (int c = 0; c < 3; c++) { csz[c * NBB + bb] = ctr[c]; csz[(3 + c) * NBB + bb] = sz[c]; }
    }
    for (int i = threadIdx.x; i < NV; i += 256) {
#pragma unroll
        for (int c = 0; c < 3; c++)
            v[((size_t)i * 3 + c) * NBB + bb] = (src[i * 3 + c] - ctr[c]) / sz[c];
        sulc[(size_t)i * NBB + bb] = 0.f;
    }
}

// ---------------- per-step: geometry -> feats[9] = (v, n, 0.5*lap) ----------------
// ring-sorted adjacency: load d neighbor positions ONCE; face t = (ring[t], ring[t+1])
__global__ __launch_bounds__(256) void k_geom(const float* __restrict__ v,
                                              const int* __restrict__ deg,
                                              const int* __restrict__ nbrB,
                                              float* __restrict__ feat) {
    int g = swiz(blockIdx.x);
    if (g >= GROUPS) return;
    int t = threadIdx.x, lane = t & 63;
    int vbase = rfl(g * VPB + (t >> 6) * VPW);
    float sgn = (lane < BATCH) ? 1.f : -1.f;
#pragma unroll
    for (int q = 0; q < VPW; q++) {
        int vi = vbase + q;
        bool act = (vi < NV);
        int vil = act ? vi : NV - 1;
        float ax_ = v[((size_t)vil * 3 + 0) * NBB + lane];
        float ay_ = v[((size_t)vil * 3 + 1) * NBB + lane];
        float az_ = v[((size_t)vil * 3 + 2) * NBB + lane];
        int d = rfl(deg[vil]);
        float px[6], py[6], pz[6];
#pragma unroll
        for (int k = 0; k < 6; k++) {
            if (k < d) {
                int u = rfl(nbrB[vil * 6 + k]);
                px[k] = v[((size_t)u * 3 + 0) * NBB + lane];
                py[k] = v[((size_t)u * 3 + 1) * NBB + lane];
                pz[k] = v[((size_t)u * 3 + 2) * NBB + lane];
            } else { px[k] = 0.f; py[k] = 0.f; pz[k] = 0.f; }
        }
        float vnx = 0.f, vny = 0.f, vnz = 0.f, lx = 0.f, ly = 0.f, lz = 0.f;
#pragma unroll
        for (int k = 0; k < 6; k++) {
            if (k < d) {
                bool wrap = (k + 1 == d);
                float bx = px[k], by = py[k], bz = pz[k];
                float cx = wrap ? px[0] : px[(k + 1) % 6];
                float cy = wrap ? py[0] : py[(k + 1) % 6];
                float cz = wrap ? pz[0] : pz[(k + 1) % 6];
                float e1x = bx - ax_, e1y = by - ay_, e1z = bz - az_;   // B - A
                float e2x = cx - ax_, e2y = cy - ay_, e2z = cz - az_;   // C - A
                float fnx = e1y * e2z - e1z * e2y;                      // face normal
                float fny = e1z * e2x - e1x * e2z;
                float fnz = e1x * e2y - e1y * e2x;
                vnx += fnx; vny += fny; vnz += fnz;
                float denom = sqrtf(fnx * fnx + fny * fny + fnz * fnz) + EPSV; // 2*area+eps
                float ux = cx - bx, uy = cy - by, uz = cz - bz;
                float wx = ax_ - bx, wy = ay_ - by, wz = az_ - bz;
                float cB = (ux * wx + uy * wy + uz * wz) / denom;       // cot at B
                float rx = ax_ - cx, ry = ay_ - cy, rz = az_ - cz;
                float sx = bx - cx, sy = by - cy, sz2 = bz - cz;
                float cC = (rx * sx + ry * sy + rz * sz2) / denom;      // cot at C
                lx += cC * e1x + cB * e2x;                              // A gets cC*(B-A)+cB*(C-A)
                ly += cC * e1y + cB * e2y;
                lz += cC * e1z + cB * e2z;
            }
        }
        vnx *= sgn; vny *= sgn; vnz *= sgn;
        float nn = sqrtf(vnx * vnx + vny * vny + vnz * vnz) + EPSV;
        if (act) {
            float* fp = feat + (size_t)vi * 9 * NBB + lane;
            fp[0 * NBB] = ax_; fp[1 * NBB] = ay_; fp[2 * NBB] = az_;
            fp[3 * NBB] = vnx / nn; fp[4 * NBB] = vny / nn; fp[5 * NBB] = vnz / nn;
            fp[6 * NBB] = 0.5f * lx; fp[7 * NBB] = 0.5f * ly; fp[8 * NBB] = 0.5f * lz;
        }
    }
}

// ---------------- per-step: layer1  h = relu(feats@W1s + mean_nbr(feats)@W1n + b1) ----------------
__global__ __launch_bounds__(256, 4) void k_layer1(const float* __restrict__ feat,
                                                   const int* __restrict__ deg,
                                                   const int* __restrict__ nbrB,
                                                   const float* __restrict__ W1s,
                                                   const float* __restrict__ W1n,
                                                   const float* __restrict__ b1,
                                                   float* __restrict__ h) {
    __shared__ float sWs[16 * 12], sWn[16 * 12], sb[16];   // transposed [j][i], row pad 9->12
    int t = threadIdx.x;
    if (t < 144) {
        int i = t >> 4, j = t & 15;
        sWs[j * 12 + i] = W1s[t];
        sWn[j * 12 + i] = W1n[t];
    }
    if (t < 16) sb[t] = b1[t];
    __syncthreads();
    int g = swiz(blockIdx.x);
    if (g >= GROUPS) return;
    int lane = t & 63;
    int vbase = rfl(g * VPB + (t >> 6) * VPW);
    float own[VPW][9], m[VPW][9];
#pragma unroll
    for (int q = 0; q < VPW; q++) {
        int vi = vbase + q;
        int vil = (vi < NV) ? vi : NV - 1;
        const float* fp = feat + (size_t)vil * 9 * NBB + lane;
#pragma unroll
        for (int i = 0; i < 9; i++) { own[q][i] = fp[i * NBB]; m[q][i] = 0.f; }
        int d = rfl(deg[vil]);
#pragma unroll
        for (int k = 0; k < 6; k++) {
            if (k < d) {
                int u = rfl(nbrB[vil * 6 + k]);
                const float* fu = feat + (size_t)u * 9 * NBB + lane;
#pragma unroll
                for (int i = 0; i < 9; i++) m[q][i] += fu[i * NBB];
            }
        }
        float inv = 1.f / (float)d;
#pragma unroll
        for (int i = 0; i < 9; i++) m[q][i] *= inv;
    }
#pragma unroll 4
    for (int j = 0; j < 16; j++) {
        float acc[VPW];
#pragma unroll
        for (int q = 0; q < VPW; q++) acc[q] = sb[j];
#pragma unroll
        for (int i = 0; i < 9; i++) {
            float ws = sWs[j * 12 + i], wn = sWn[j * 12 + i];
#pragma unroll
            for (int q = 0; q < VPW; q++) acc[q] += own[q][i] * ws + m[q][i] * wn;
        }
#pragma unroll
        for (int q = 0; q < VPW; q++) {
            int vi = vbase + q;
            if (vi < NV) h[((size_t)vi * 16 + j) * NBB + lane] = fmaxf(acc[q], 0.f);
        }
    }
}

// ---------------- per-step: layer2 + fused head + state update ----------------
// chunked m-accumulation (2 halves of 8 ch) keeps live VGPRs ~80 -> 4 waves/SIMD w/o spill
__global__ __launch_bounds__(256, 4) void k_layer2(const float* __restrict__ h,
                                                   const float* __restrict__ feat,
                                                   const int* __restrict__ deg,
                                                   const int* __restrict__ nbrB,
                                                   const float* __restrict__ W2s,
                                                   const float* __restrict__ W2n,
                                                   const float* __restrict__ b2,
                                                   const float* __restrict__ Wo,
                                                   const float* __restrict__ bo,
                                                   float* __restrict__ v,
                                                   float* __restrict__ sulc) {
    __shared__ float sWs[256], sWn[256], sb[16], sWo[48], sbo[3];  // transposed [j][i]
    int t = threadIdx.x;
    {
        int i = t >> 4, j = t & 15;
        sWs[j * 16 + i] = W2s[t];
        sWn[j * 16 + i] = W2n[t];
    }
    if (t < 48) { int i = t / 3, c = t - 3 * i; sWo[c * 16 + i] = Wo[t]; }
    if (t < 16) sb[t] = b2[t];
    if (t < 3)  sbo[t] = bo[t];
    __syncthreads();
    int g = swiz(blockIdx.x);
    if (g >= GROUPS) return;
    int lane = t & 63;
    int vbase = rfl(g * VPB + (t >> 6) * VPW);
    int vil[VPW], d[VPW];
    float inv[VPW];
#pragma unroll
    for (int q = 0; q < VPW; q++) {
        int vi = vbase + q;
        vil[q] = (vi < NV) ? vi : NV - 1;
        d[q] = rfl(deg[vil[q]]);
        inv[q] = 1.f / (float)d[q];
    }
    float acc[VPW][16];
#pragma unroll
    for (int q = 0; q < VPW; q++)
#pragma unroll
        for (int j = 0; j < 16; j++) acc[q][j] = sb[j];

#pragma unroll
    for (int half = 0; half < 2; half++) {
        int cb = half * 8;   // channel base
        float own8[VPW][8], m8[VPW][8];
#pragma unroll
        for (int q = 0; q < VPW; q++) {
            const float* hp = h + ((size_t)vil[q] * 16 + cb) * NBB + lane;
#pragma unroll
            for (int i = 0; i < 8; i++) { own8[q][i] = hp[i * NBB]; m8[q][i] = 0.f; }
#pragma unroll
            for (int k = 0; k < 6; k++) {
                if (k < d[q]) {
                    int u = rfl(nbrB[vil[q] * 6 + k]);
                    const float* hu = h + ((size_t)u * 16 + cb) * NBB + lane;
#pragma unroll
                    for (int i = 0; i < 8; i++) m8[q][i] += hu[i * NBB];
                }
            }
#pragma unroll
            for (int i = 0; i < 8; i++) m8[q][i] *= inv[q];
        }
#pragma unroll
        for (int j = 0; j < 16; j++) {
#pragma unroll
            for (int i = 0; i < 8; i++) {
                float ws = sWs[j * 16 + cb + i], wn = sWn[j * 16 + cb + i];
#pragma unroll
                for (int q = 0; q < VPW; q++)
                    acc[q][j] += own8[q][i] * ws + m8[q][i] * wn;
            }
        }
    }

    float dv[VPW][3];
#pragma unroll
    for (int q = 0; q < VPW; q++)
#pragma unroll
        for (int c = 0; c < 3; c++) dv[q][c] = sbo[c];
#pragma unroll
    for (int j = 0; j < 16; j++) {
        float wo0 = sWo[0 * 16 + j], wo1 = sWo[1 * 16 + j], wo2 = sWo[2 * 16 + j];
#pragma unroll
        for (int q = 0; q < VPW; q++) {
            float h2 = fmaxf(acc[q][j], 0.f);   // fused head: h2 never materialized
            dv[q][0] += h2 * wo0;
            dv[q][1] += h2 * wo1;
            dv[q][2] += h2 * wo2;
        }
    }
#pragma unroll
    for (int q = 0; q < VPW; q++) {
        int vi = vbase + q;
        if (vi >= NV) break;
        float* vp = v + (size_t)vi * 3 * NBB + lane;
        const float* np_ = feat + ((size_t)vi * 9 + 3) * NBB + lane;  // this step's normals
        vp[0 * NBB] += STEPSZ * dv[q][0];
        vp[1 * NBB] += STEPSZ * dv[q][1];
        vp[2 * NBB] += STEPSZ * dv[q][2];
        sulc[(size_t)vi * NBB + lane] +=
            STEPSZ * (np_[0 * NBB] * dv[q][0] + np_[1 * NBB] * dv[q][1] + np_[2 * NBB] * dv[q][2]);
    }
}

// ---------------- output: (2,B,V,4) = (v*size, sulc) ----------------
__global__ __launch_bounds__(256) void k_out(const float* __restrict__ v,
                                             const float* __restrict__ sulc,
                                             const float* __restrict__ csz,
                                             float4* __restrict__ out) {
    int vi = blockIdx.x * 256 + threadIdx.x;
    int bb = blockIdx.y;
    if (vi >= NV) return;
    float4 o;
    o.x = v[((size_t)vi * 3 + 0) * NBB + bb] * csz[(3 + 0) * NBB + bb];
    o.y = v[((size_t)vi * 3 + 1) * NBB + bb] * csz[(3 + 1) * NBB + bb];
    o.z = v[((size_t)vi * 3 + 2) * NBB + bb] * csz[(3 + 2) * NBB + bb];
    o.w = sulc[(size_t)vi * NBB + bb];
    out[(size_t)bb * NV + vi] = o;
}

extern "C" void kernel_launch(void* const* d_in, const int* in_sizes, int n_in,
                              void* d_out, int out_size, void* d_ws, size_t ws_size,
                              hipStream_t stream) {
    const float* lh  = (const float*)d_in[0];
    const float* rh  = (const float*)d_in[1];
    const float* W1s = (const float*)d_in[2];
    const float* W1n = (const float*)d_in[3];
    const float* b1  = (const float*)d_in[4];
    const float* W2s = (const float*)d_in[5];
    const float* W2n = (const float*)d_in[6];
    const float* b2  = (const float*)d_in[7];
    const float* Wo  = (const float*)d_in[8];
    const float* bo  = (const float*)d_in[9];
    const int* faces = (const int*)d_in[10];

    float* ws   = (float*)d_ws;
    float* v    = ws + OFF_V;
    float* sulc = ws + OFF_SULC;
    float* feat = ws + OFF_FEAT;
    float* h    = ws + OFF_H;
    float* csz  = ws + OFF_CSZ;
    int* ibase  = (int*)(ws + OFF_INT);
    int* deg    = ibase;
    int* nbrB   = ibase + NV;
    int* nbrC   = ibase + NV + NV * 6;

    dim3 gv(NBLK);

    k_zero_deg<<<(NV + 255) / 256, 256, 0, stream>>>(deg);
    k_build<<<(NF + 255) / 256, 256, 0, stream>>>(faces, deg, nbrB, nbrC);
    k_sortring<<<(NV + 255) / 256, 256, 0, stream>>>(deg, nbrB, nbrC);
    k_norm<<<NBB, 256, 0, stream>>>(lh, rh, v, sulc, csz);

    for (int s = 0; s < NSTEPS; s++) {
        k_geom<<<gv, 256, 0, stream>>>(v, deg, nbrB, feat);
        k_layer1<<<gv, 256, 0, stream>>>(feat, deg, nbrB, W1s, W1n, b1, h);
        k_layer2<<<gv, 256, 0, stream>>>(h, feat, deg, nbrB, W2s, W2n, b2, Wo, bo, v, sulc);
    }
    k_out<<<dim3((NV + 255) / 256, NBB), 256, 0, stream>>>(v, sulc, csz, (float4*)d_out);
}

// Round 6
// 2488.757 us; speedup vs baseline: 1.9932x; 1.9932x over previous
//
#include <hip/hip_runtime.h>
#include <stdint.h>

#define BATCH 32
#define NV    10242
#define NF    20480
#define NBB   64          // 2 hemis * 32 batches ; lane = bb
#define NSTEPS 10
#define STEPSZ 0.1f
#define EPSV   1e-8f

#define VPW    2                          // vertices per wave
#define VPB    8                          // vertices per block (4 waves * VPW)
#define GROUPS ((NV + VPB - 1) / VPB)     // 1281
#define GPC    ((GROUPS + 7) / 8)         // 161 groups per XCD chunk
#define NBLK   (GPC * 8)                  // 1288 blocks

// NOTE (R3/R5 post-mortem): NEVER pass a second arg to __launch_bounds__ here.
// (256,3) forced VGPR=84 and (256,4) forced VGPR=64 -> 140-770 MB of scratch
// spill traffic per dispatch. Uncapped (R2) the allocator picks ~136 VGPR, no spill.

// ---------------- workspace layout (all state transposed to [V][ch][NBB]) ----------------
static constexpr size_t OFF_V    = 0;                               // [V][3][NBB]  f32
static constexpr size_t OFF_SULC = OFF_V    + (size_t)NV * 3 * NBB; // [V][NBB]     f32
static constexpr size_t OFF_FEAT = OFF_SULC + (size_t)NV * NBB;     // [V][9][NBB]  f32 (v,n,lap)
static constexpr size_t OFF_H    = OFF_FEAT + (size_t)NV * 9 * NBB; // [V][16][NBB] f32
static constexpr size_t OFF_CSZ  = OFF_H    + (size_t)NV * 16 * NBB;// [6][NBB]
static constexpr size_t OFF_INT  = OFF_CSZ  + 6 * NBB;
// int region: deg[NV], nbrB[NV*6] (ring-sorted after k_sortring), nbrC[NV*6]

__device__ __forceinline__ int rfl(int x) { return __builtin_amdgcn_readfirstlane(x); }
// XCD swizzle: chunk = blockIdx%8 owns contiguous GPC groups -> contiguous vertex range per XCD L2
__device__ __forceinline__ int swiz(int b) { return (b & 7) * GPC + (b >> 3); }

// ---------------- adjacency build ----------------
__global__ __launch_bounds__(256) void k_zero_deg(int* deg) {
    int i = blockIdx.x * 256 + threadIdx.x;
    if (i < NV) deg[i] = 0;
}

__global__ __launch_bounds__(256) void k_build(const int* __restrict__ faces,
                                               int* deg, int* nbrB, int* nbrC) {
    int fi = blockIdx.x * 256 + threadIdx.x;
    if (fi >= NF) return;
    int vv[3] = {faces[fi * 3 + 0], faces[fi * 3 + 1], faces[fi * 3 + 2]};
#pragma unroll
    for (int c = 0; c < 3; c++) {
        int vtx = vv[c];
        int s = atomicAdd(&deg[vtx], 1);
        nbrB[vtx * 6 + s] = vv[(c + 1) % 3];   // next corner (dedup'd neighbor)
        nbrC[vtx * 6 + s] = vv[(c + 2) % 3];   // prev corner
    }
}

// sort each 1-ring so that C_t == B_{t+1}: consecutive ring entries form each face's (B,C)
__global__ __launch_bounds__(256) void k_sortring(const int* __restrict__ deg,
                                                  int* nbrB, const int* __restrict__ nbrC) {
    int vi = blockIdx.x * 256 + threadIdx.x;
    if (vi >= NV) return;
    int d = deg[vi];
    int b[6], c[6];
#pragma unroll
    for (int k = 0; k < 6; k++) {
        b[k] = (k < d) ? nbrB[vi * 6 + k] : -1;
        c[k] = (k < d) ? nbrC[vi * 6 + k] : -2;
    }
    int ord[6];
    ord[0] = b[0];
    int cur = c[0];
#pragma unroll
    for (int t = 1; t < 6; t++) {
        int nxt = cur, nc = cur;
#pragma unroll
        for (int k = 0; k < 6; k++)
            if (b[k] == cur) { nxt = b[k]; nc = c[k]; }
        ord[t] = nxt;
        cur = nc;
    }
#pragma unroll
    for (int t = 0; t < 6; t++)
        if (t < d) nbrB[vi * 6 + t] = ord[t];
}

// ---------------- bbox + normalize + transpose-in (one block per bb) ----------------
__global__ __launch_bounds__(256) void k_norm(const float* __restrict__ lh,
                                              const float* __restrict__ rh,
                                              float* __restrict__ v,
                                              float* __restrict__ sulc,
                                              float* __restrict__ csz) {
    int bb = blockIdx.x;
    const float* src = (bb < BATCH) ? (lh + (size_t)bb * NV * 3)
                                    : (rh + (size_t)(bb - BATCH) * NV * 3);
    __shared__ float smin[3][256], smax[3][256];
    float mn[3] = {1e30f, 1e30f, 1e30f}, mx[3] = {-1e30f, -1e30f, -1e30f};
    for (int i = threadIdx.x; i < NV; i += 256) {
#pragma unroll
        for (int c = 0; c < 3; c++) {
            float x = src[i * 3 + c];
            mn[c] = fminf(mn[c], x);
            mx[c] = fmaxf(mx[c], x);
        }
    }
#pragma unroll
    for (int c = 0; c < 3; c++) { smin[c][threadIdx.x] = mn[c]; smax[c][threadIdx.x] = mx[c]; }
    __syncthreads();
    for (int s = 128; s > 0; s >>= 1) {
        if (threadIdx.x < s) {
#pragma unroll
            for (int c = 0; c < 3; c++) {
                smin[c][threadIdx.x] = fminf(smin[c][threadIdx.x], smin[c][threadIdx.x + s]);
                smax[c][threadIdx.x] = fmaxf(smax[c][threadIdx.x], smax[c][threadIdx.x + s]);
            }
        }
        __syncthreads();
    }
    float ctr[3], sz[3];
#pragma unroll
    for (int c = 0; c < 3; c++) {
        ctr[c] = 0.5f * (smin[c][0] + smax[c][0]);
        sz[c]  = smax[c][0] - ctr[c];
    }
    if (threadIdx.x == 0) {
#pragma unroll
        for (int c = 0; c < 3; c++) { csz[c * NBB + bb] = ctr[c]; csz[(3 + c) * NBB + bb] = sz[c]; }
    }
    for (int i = threadIdx.x; i < NV; i += 256) {
#pragma unroll
        for (int c = 0; c < 3; c++)
            v[((size_t)i * 3 + c) * NBB + bb] = (src[i * 3 + c] - ctr[c]) / sz[c];
        sulc[(size_t)i * NBB + bb] = 0.f;
    }
}

// ---------------- per-step: geometry -> feats[9] = (v, n, 0.5*lap) ----------------
// ring-sorted adjacency: load d neighbor positions ONCE; face t = (ring[t], ring[t+1])
__global__ __launch_bounds__(256) void k_geom(const float* __restrict__ v,
                                              const int* __restrict__ deg,
                                              const int* __restrict__ nbrB,
                                              float* __restrict__ feat) {
    int g = swiz(blockIdx.x);
    if (g >= GROUPS) return;
    int t = threadIdx.x, lane = t & 63;
    int vbase = rfl(g * VPB + (t >> 6) * VPW);
    float sgn = (lane < BATCH) ? 1.f : -1.f;
#pragma unroll
    for (int q = 0; q < VPW; q++) {
        int vi = vbase + q;
        bool act = (vi < NV);
        int vil = act ? vi : NV - 1;
        float ax_ = v[((size_t)vil * 3 + 0) * NBB + lane];
        float ay_ = v[((size_t)vil * 3 + 1) * NBB + lane];
        float az_ = v[((size_t)vil * 3 + 2) * NBB + lane];
        int d = rfl(deg[vil]);
        float px[6], py[6], pz[6];
#pragma unroll
        for (int k = 0; k < 6; k++) {
            if (k < d) {
                int u = rfl(nbrB[vil * 6 + k]);
                px[k] = v[((size_t)u * 3 + 0) * NBB + lane];
                py[k] = v[((size_t)u * 3 + 1) * NBB + lane];
                pz[k] = v[((size_t)u * 3 + 2) * NBB + lane];
            } else { px[k] = 0.f; py[k] = 0.f; pz[k] = 0.f; }
        }
        float vnx = 0.f, vny = 0.f, vnz = 0.f, lx = 0.f, ly = 0.f, lz = 0.f;
#pragma unroll
        for (int k = 0; k < 6; k++) {
            if (k < d) {
                bool wrap = (k + 1 == d);
                float bx = px[k], by = py[k], bz = pz[k];
                float cx = wrap ? px[0] : px[(k + 1) % 6];
                float cy = wrap ? py[0] : py[(k + 1) % 6];
                float cz = wrap ? pz[0] : pz[(k + 1) % 6];
                float e1x = bx - ax_, e1y = by - ay_, e1z = bz - az_;   // B - A
                float e2x = cx - ax_, e2y = cy - ay_, e2z = cz - az_;   // C - A
                float fnx = e1y * e2z - e1z * e2y;                      // face normal
                float fny = e1z * e2x - e1x * e2z;
                float fnz = e1x * e2y - e1y * e2x;
                vnx += fnx; vny += fny; vnz += fnz;
                float denom = sqrtf(fnx * fnx + fny * fny + fnz * fnz) + EPSV; // 2*area+eps
                float ux = cx - bx, uy = cy - by, uz = cz - bz;
                float wx = ax_ - bx, wy = ay_ - by, wz = az_ - bz;
                float cB = (ux * wx + uy * wy + uz * wz) / denom;       // cot at B
                float rx = ax_ - cx, ry = ay_ - cy, rz = az_ - cz;
                float sx = bx - cx, sy = by - cy, sz2 = bz - cz;
                float cC = (rx * sx + ry * sy + rz * sz2) / denom;      // cot at C
                lx += cC * e1x + cB * e2x;                              // A gets cC*(B-A)+cB*(C-A)
                ly += cC * e1y + cB * e2y;
                lz += cC * e1z + cB * e2z;
            }
        }
        vnx *= sgn; vny *= sgn; vnz *= sgn;
        float nn = sqrtf(vnx * vnx + vny * vny + vnz * vnz) + EPSV;
        if (act) {
            float* fp = feat + (size_t)vi * 9 * NBB + lane;
            fp[0 * NBB] = ax_; fp[1 * NBB] = ay_; fp[2 * NBB] = az_;
            fp[3 * NBB] = vnx / nn; fp[4 * NBB] = vny / nn; fp[5 * NBB] = vnz / nn;
            fp[6 * NBB] = 0.5f * lx; fp[7 * NBB] = 0.5f * ly; fp[8 * NBB] = 0.5f * lz;
        }
    }
}

// ---------------- per-step: layer1  h = relu(feats@W1s + mean_nbr(feats)@W1n + b1) ----------------
__global__ __launch_bounds__(256) void k_layer1(const float* __restrict__ feat,
                                                const int* __restrict__ deg,
                                                const int* __restrict__ nbrB,
                                                const float* __restrict__ W1s,
                                                const float* __restrict__ W1n,
                                                const float* __restrict__ b1,
                                                float* __restrict__ h) {
    __shared__ float sWs[16 * 12], sWn[16 * 12], sb[16];   // transposed [j][i], row pad 9->12
    int t = threadIdx.x;
    if (t < 144) {
        int i = t >> 4, j = t & 15;
        sWs[j * 12 + i] = W1s[t];
        sWn[j * 12 + i] = W1n[t];
    }
    if (t < 16) sb[t] = b1[t];
    __syncthreads();
    int g = swiz(blockIdx.x);
    if (g >= GROUPS) return;
    int lane = t & 63;
    int vbase = rfl(g * VPB + (t >> 6) * VPW);
    float own[VPW][9], m[VPW][9];
#pragma unroll
    for (int q = 0; q < VPW; q++) {
        int vi = vbase + q;
        int vil = (vi < NV) ? vi : NV - 1;
        const float* fp = feat + (size_t)vil * 9 * NBB + lane;
#pragma unroll
        for (int i = 0; i < 9; i++) { own[q][i] = fp[i * NBB]; m[q][i] = 0.f; }
        int d = rfl(deg[vil]);
#pragma unroll
        for (int k = 0; k < 6; k++) {
            if (k < d) {
                int u = rfl(nbrB[vil * 6 + k]);
                const float* fu = feat + (size_t)u * 9 * NBB + lane;
#pragma unroll
                for (int i = 0; i < 9; i++) m[q][i] += fu[i * NBB];
            }
        }
        float inv = 1.f / (float)d;
#pragma unroll
        for (int i = 0; i < 9; i++) m[q][i] *= inv;
    }
#pragma unroll 4
    for (int j = 0; j < 16; j++) {
        float acc[VPW];
#pragma unroll
        for (int q = 0; q < VPW; q++) acc[q] = sb[j];
#pragma unroll
        for (int i = 0; i < 9; i++) {
            float ws = sWs[j * 12 + i], wn = sWn[j * 12 + i];
#pragma unroll
            for (int q = 0; q < VPW; q++) acc[q] += own[q][i] * ws + m[q][i] * wn;
        }
#pragma unroll
        for (int q = 0; q < VPW; q++) {
            int vi = vbase + q;
            if (vi < NV) h[((size_t)vi * 16 + j) * NBB + lane] = fmaxf(acc[q], 0.f);
        }
    }
}

// ---------------- per-step: layer2 + fused head + state update ----------------
// chunked m-accumulation (2 halves of 8 ch) keeps natural live VGPRs moderate; allocator uncapped
__global__ __launch_bounds__(256) void k_layer2(const float* __restrict__ h,
                                                const float* __restrict__ feat,
                                                const int* __restrict__ deg,
                                                const int* __restrict__ nbrB,
                                                const float* __restrict__ W2s,
                                                const float* __restrict__ W2n,
                                                const float* __restrict__ b2,
                                                const float* __restrict__ Wo,
                                                const float* __restrict__ bo,
                                                float* __restrict__ v,
                                                float* __restrict__ sulc) {
    __shared__ float sWs[256], sWn[256], sb[16], sWo[48], sbo[3];  // transposed [j][i]
    int t = threadIdx.x;
    {
        int i = t >> 4, j = t & 15;
        sWs[j * 16 + i] = W2s[t];
        sWn[j * 16 + i] = W2n[t];
    }
    if (t < 48) { int i = t / 3, c = t - 3 * i; sWo[c * 16 + i] = Wo[t]; }
    if (t < 16) sb[t] = b2[t];
    if (t < 3)  sbo[t] = bo[t];
    __syncthreads();
    int g = swiz(blockIdx.x);
    if (g >= GROUPS) return;
    int lane = t & 63;
    int vbase = rfl(g * VPB + (t >> 6) * VPW);
    int vil[VPW], d[VPW];
    float inv[VPW];
#pragma unroll
    for (int q = 0; q < VPW; q++) {
        int vi = vbase + q;
        vil[q] = (vi < NV) ? vi : NV - 1;
        d[q] = rfl(deg[vil[q]]);
        inv[q] = 1.f / (float)d[q];
    }
    float acc[VPW][16];
#pragma unroll
    for (int q = 0; q < VPW; q++)
#pragma unroll
        for (int j = 0; j < 16; j++) acc[q][j] = sb[j];

#pragma unroll
    for (int half = 0; half < 2; half++) {
        int cb = half * 8;   // channel base
        float own8[VPW][8], m8[VPW][8];
#pragma unroll
        for (int q = 0; q < VPW; q++) {
            const float* hp = h + ((size_t)vil[q] * 16 + cb) * NBB + lane;
#pragma unroll
            for (int i = 0; i < 8; i++) { own8[q][i] = hp[i * NBB]; m8[q][i] = 0.f; }
#pragma unroll
            for (int k = 0; k < 6; k++) {
                if (k < d[q]) {
                    int u = rfl(nbrB[vil[q] * 6 + k]);
                    const float* hu = h + ((size_t)u * 16 + cb) * NBB + lane;
#pragma unroll
                    for (int i = 0; i < 8; i++) m8[q][i] += hu[i * NBB];
                }
            }
#pragma unroll
            for (int i = 0; i < 8; i++) m8[q][i] *= inv[q];
        }
#pragma unroll
        for (int j = 0; j < 16; j++) {
#pragma unroll
            for (int i = 0; i < 8; i++) {
                float ws = sWs[j * 16 + cb + i], wn = sWn[j * 16 + cb + i];
#pragma unroll
                for (int q = 0; q < VPW; q++)
                    acc[q][j] += own8[q][i] * ws + m8[q][i] * wn;
            }
        }
    }

    float dv[VPW][3];
#pragma unroll
    for (int q = 0; q < VPW; q++)
#pragma unroll
        for (int c = 0; c < 3; c++) dv[q][c] = sbo[c];
#pragma unroll
    for (int j = 0; j < 16; j++) {
        float wo0 = sWo[0 * 16 + j], wo1 = sWo[1 * 16 + j], wo2 = sWo[2 * 16 + j];
#pragma unroll
        for (int q = 0; q < VPW; q++) {
            float h2 = fmaxf(acc[q][j], 0.f);   // fused head: h2 never materialized
            dv[q][0] += h2 * wo0;
            dv[q][1] += h2 * wo1;
            dv[q][2] += h2 * wo2;
        }
    }
#pragma unroll
    for (int q = 0; q < VPW; q++) {
        int vi = vbase + q;
        if (vi >= NV) break;
        float* vp = v + (size_t)vi * 3 * NBB + lane;
        const float* np_ = feat + ((size_t)vi * 9 + 3) * NBB + lane;  // this step's normals
        vp[0 * NBB] += STEPSZ * dv[q][0];
        vp[1 * NBB] += STEPSZ * dv[q][1];
        vp[2 * NBB] += STEPSZ * dv[q][2];
        sulc[(size_t)vi * NBB + lane] +=
            STEPSZ * (np_[0 * NBB] * dv[q][0] + np_[1 * NBB] * dv[q][1] + np_[2 * NBB] * dv[q][2]);
    }
}

// ---------------- output: (2,B,V,4) = (v*size, sulc) ----------------
__global__ __launch_bounds__(256) void k_out(const float* __restrict__ v,
                                             const float* __restrict__ sulc,
                                             const float* __restrict__ csz,
                                             float4* __restrict__ out) {
    int vi = blockIdx.x * 256 + threadIdx.x;
    int bb = blockIdx.y;
    if (vi >= NV) return;
    float4 o;
    o.x = v[((size_t)vi * 3 + 0) * NBB + bb] * csz[(3 + 0) * NBB + bb];
    o.y = v[((size_t)vi * 3 + 1) * NBB + bb] * csz[(3 + 1) * NBB + bb];
    o.z = v[((size_t)vi * 3 + 2) * NBB + bb] * csz[(3 + 2) * NBB + bb];
    o.w = sulc[(size_t)vi * NBB + bb];
    out[(size_t)bb * NV + vi] = o;
}

extern "C" void kernel_launch(void* const* d_in, const int* in_sizes, int n_in,
                              void* d_out, int out_size, void* d_ws, size_t ws_size,
                              hipStream_t stream) {
    const float* lh  = (const float*)d_in[0];
    const float* rh  = (const float*)d_in[1];
    const float* W1s = (const float*)d_in[2];
    const float* W1n = (const float*)d_in[3];
    const float* b1  = (const float*)d_in[4];
    const float* W2s = (const float*)d_in[5];
    const float* W2n = (const float*)d_in[6];
    const float* b2  = (const float*)d_in[7];
    const float* Wo  = (const float*)d_in[8];
    const float* bo  = (const float*)d_in[9];
    const int* faces = (const int*)d_in[10];

    float* ws   = (float*)d_ws;
    float* v    = ws + OFF_V;
    float* sulc = ws + OFF_SULC;
    float* feat = ws + OFF_FEAT;
    float* h    = ws + OFF_H;
    float* csz  = ws + OFF_CSZ;
    int* ibase  = (int*)(ws + OFF_INT);
    int* deg    = ibase;
    int* nbrB   = ibase + NV;
    int* nbrC   = ibase + NV + NV * 6;

    dim3 gv(NBLK);

    k_zero_deg<<<(NV + 255) / 256, 256, 0, stream>>>(deg);
    k_build<<<(NF + 255) / 256, 256, 0, stream>>>(faces, deg, nbrB, nbrC);
    k_sortring<<<(NV + 255) / 256, 256, 0, stream>>>(deg, nbrB, nbrC);
    k_norm<<<NBB, 256, 0, stream>>>(lh, rh, v, sulc, csz);

    for (int s = 0; s < NSTEPS; s++) {
        k_geom<<<gv, 256, 0, stream>>>(v, deg, nbrB, feat);
        k_layer1<<<gv, 256, 0, stream>>>(feat, deg, nbrB, W1s, W1n, b1, h);
        k_layer2<<<gv, 256, 0, stream>>>(h, feat, deg, nbrB, W2s, W2n, b2, Wo, bo, v, sulc);
    }
    k_out<<<dim3((NV + 255) / 256, NBB), 256, 0, stream>>>(v, sulc, csz, (float4*)d_out);
}

// Round 7
// 1813.766 us; speedup vs baseline: 2.7350x; 1.3721x over previous
//
#include <hip/hip_runtime.h>
#include <stdint.h>

#define BATCH 32
#define NV    10242
#define NF    20480
#define NBB   64          // 2 hemis * 32 batches ; lane = bb
#define NSTEPS 10
#define STEPSZ 0.1f
#define EPSV   1e-8f

#define VPW    2                          // vertices per wave
#define VPB    8                          // vertices per block (4 waves * VPW)
#define GROUPS ((NV + VPB - 1) / VPB)     // 1281
#define GPC    ((GROUPS + 7) / 8)         // 161 groups per XCD chunk
#define NBLK   (GPC * 8)                  // 1288 blocks

// HARD RULES from R3/R5/R6 post-mortems:
//  1. NEVER pass a 2nd arg to __launch_bounds__ (force-caps VGPR -> 100s of MB of spill).
//  2. NEVER keep a persistent acc[VPW][16] across gather phases (R6: 256 VGPR + 180 MB spill).
//     Fuse the head so each j-column collapses to dv immediately.

// ---------------- workspace layout (all state transposed to [V][ch][NBB]) ----------------
static constexpr size_t OFF_V    = 0;                               // [V][3][NBB]  f32
static constexpr size_t OFF_SULC = OFF_V    + (size_t)NV * 3 * NBB; // [V][NBB]     f32
static constexpr size_t OFF_FEAT = OFF_SULC + (size_t)NV * NBB;     // [V][9][NBB]  f32 (v,n,lap)
static constexpr size_t OFF_H    = OFF_FEAT + (size_t)NV * 9 * NBB; // [V][16][NBB] f32
static constexpr size_t OFF_CSZ  = OFF_H    + (size_t)NV * 16 * NBB;// [6][NBB]
static constexpr size_t OFF_INT  = OFF_CSZ  + 6 * NBB;
// int region: deg[NV], nbrB[NV*6] (ring-sorted after k_sortring), nbrC[NV*6]

__device__ __forceinline__ int rfl(int x) { return __builtin_amdgcn_readfirstlane(x); }
// XCD swizzle: chunk = blockIdx%8 owns contiguous GPC groups -> contiguous vertex range per XCD L2
__device__ __forceinline__ int swiz(int b) { return (b & 7) * GPC + (b >> 3); }

// ---------------- adjacency build ----------------
__global__ __launch_bounds__(256) void k_zero_deg(int* deg) {
    int i = blockIdx.x * 256 + threadIdx.x;
    if (i < NV) deg[i] = 0;
}

__global__ __launch_bounds__(256) void k_build(const int* __restrict__ faces,
                                               int* deg, int* nbrB, int* nbrC) {
    int fi = blockIdx.x * 256 + threadIdx.x;
    if (fi >= NF) return;
    int vv[3] = {faces[fi * 3 + 0], faces[fi * 3 + 1], faces[fi * 3 + 2]};
#pragma unroll
    for (int c = 0; c < 3; c++) {
        int vtx = vv[c];
        int s = atomicAdd(&deg[vtx], 1);
        nbrB[vtx * 6 + s] = vv[(c + 1) % 3];   // next corner (dedup'd neighbor)
        nbrC[vtx * 6 + s] = vv[(c + 2) % 3];   // prev corner
    }
}

// sort each 1-ring so that C_t == B_{t+1}: consecutive ring entries form each face's (B,C)
__global__ __launch_bounds__(256) void k_sortring(const int* __restrict__ deg,
                                                  int* nbrB, const int* __restrict__ nbrC) {
    int vi = blockIdx.x * 256 + threadIdx.x;
    if (vi >= NV) return;
    int d = deg[vi];
    int b[6], c[6];
#pragma unroll
    for (int k = 0; k < 6; k++) {
        b[k] = (k < d) ? nbrB[vi * 6 + k] : -1;
        c[k] = (k < d) ? nbrC[vi * 6 + k] : -2;
    }
    int ord[6];
    ord[0] = b[0];
    int cur = c[0];
#pragma unroll
    for (int t = 1; t < 6; t++) {
        int nxt = cur, nc = cur;
#pragma unroll
        for (int k = 0; k < 6; k++)
            if (b[k] == cur) { nxt = b[k]; nc = c[k]; }
        ord[t] = nxt;
        cur = nc;
    }
#pragma unroll
    for (int t = 0; t < 6; t++)
        if (t < d) nbrB[vi * 6 + t] = ord[t];
}

// ---------------- bbox + normalize + transpose-in (one block per bb) ----------------
__global__ __launch_bounds__(256) void k_norm(const float* __restrict__ lh,
                                              const float* __restrict__ rh,
                                              float* __restrict__ v,
                                              float* __restrict__ sulc,
                                              float* __restrict__ csz) {
    int bb = blockIdx.x;
    const float* src = (bb < BATCH) ? (lh + (size_t)bb * NV * 3)
                                    : (rh + (size_t)(bb - BATCH) * NV * 3);
    __shared__ float smin[3][256], smax[3][256];
    float mn[3] = {1e30f, 1e30f, 1e30f}, mx[3] = {-1e30f, -1e30f, -1e30f};
    for (int i = threadIdx.x; i < NV; i += 256) {
#pragma unroll
        for (int c = 0; c < 3; c++) {
            float x = src[i * 3 + c];
            mn[c] = fminf(mn[c], x);
            mx[c] = fmaxf(mx[c], x);
        }
    }
#pragma unroll
    for (int c = 0; c < 3; c++) { smin[c][threadIdx.x] = mn[c]; smax[c][threadIdx.x] = mx[c]; }
    __syncthreads();
    for (int s = 128; s > 0; s >>= 1) {
        if (threadIdx.x < s) {
#pragma unroll
            for (int c = 0; c < 3; c++) {
                smin[c][threadIdx.x] = fminf(smin[c][threadIdx.x], smin[c][threadIdx.x + s]);
                smax[c][threadIdx.x] = fmaxf(smax[c][threadIdx.x], smax[c][threadIdx.x + s]);
            }
        }
        __syncthreads();
    }
    float ctr[3], sz[3];
#pragma unroll
    for (int c = 0; c < 3; c++) {
        ctr[c] = 0.5f * (smin[c][0] + smax[c][0]);
        sz[c]  = smax[c][0] - ctr[c];
    }
    if (threadIdx.x == 0) {
#pragma unroll
        for (int c = 0; c < 3; c++) { csz[c * NBB + bb] = ctr[c]; csz[(3 + c) * NBB + bb] = sz[c]; }
    }
    for (int i = threadIdx.x; i < NV; i += 256) {
#pragma unroll
        for (int c = 0; c < 3; c++)
            v[((size_t)i * 3 + c) * NBB + bb] = (src[i * 3 + c] - ctr[c]) / sz[c];
        sulc[(size_t)i * NBB + bb] = 0.f;
    }
}

// ---------------- per-step: geometry -> feats[9] = (v, n, 0.5*lap) ----------------
// ring-sorted adjacency: load d neighbor positions ONCE; face t = (ring[t], ring[t+1])
__global__ __launch_bounds__(256) void k_geom(const float* __restrict__ v,
                                              const int* __restrict__ deg,
                                              const int* __restrict__ nbrB,
                                              float* __restrict__ feat) {
    int g = swiz(blockIdx.x);
    if (g >= GROUPS) return;
    int t = threadIdx.x, lane = t & 63;
    int vbase = rfl(g * VPB + (t >> 6) * VPW);
    float sgn = (lane < BATCH) ? 1.f : -1.f;
#pragma unroll
    for (int q = 0; q < VPW; q++) {
        int vi = vbase + q;
        bool act = (vi < NV);
        int vil = act ? vi : NV - 1;
        float ax_ = v[((size_t)vil * 3 + 0) * NBB + lane];
        float ay_ = v[((size_t)vil * 3 + 1) * NBB + lane];
        float az_ = v[((size_t)vil * 3 + 2) * NBB + lane];
        int d = rfl(deg[vil]);
        float px[6], py[6], pz[6];
#pragma unroll
        for (int k = 0; k < 6; k++) {
            if (k < d) {
                int u = rfl(nbrB[vil * 6 + k]);
                px[k] = v[((size_t)u * 3 + 0) * NBB + lane];
                py[k] = v[((size_t)u * 3 + 1) * NBB + lane];
                pz[k] = v[((size_t)u * 3 + 2) * NBB + lane];
            } else { px[k] = 0.f; py[k] = 0.f; pz[k] = 0.f; }
        }
        float vnx = 0.f, vny = 0.f, vnz = 0.f, lx = 0.f, ly = 0.f, lz = 0.f;
#pragma unroll
        for (int k = 0; k < 6; k++) {
            if (k < d) {
                bool wrap = (k + 1 == d);
                float bx = px[k], by = py[k], bz = pz[k];
                float cx = wrap ? px[0] : px[(k + 1) % 6];
                float cy = wrap ? py[0] : py[(k + 1) % 6];
                float cz = wrap ? pz[0] : pz[(k + 1) % 6];
                float e1x = bx - ax_, e1y = by - ay_, e1z = bz - az_;   // B - A
                float e2x = cx - ax_, e2y = cy - ay_, e2z = cz - az_;   // C - A
                float fnx = e1y * e2z - e1z * e2y;                      // face normal
                float fny = e1z * e2x - e1x * e2z;
                float fnz = e1x * e2y - e1y * e2x;
                vnx += fnx; vny += fny; vnz += fnz;
                float denom = sqrtf(fnx * fnx + fny * fny + fnz * fnz) + EPSV; // 2*area+eps
                float ux = cx - bx, uy = cy - by, uz = cz - bz;
                float wx = ax_ - bx, wy = ay_ - by, wz = az_ - bz;
                float cB = (ux * wx + uy * wy + uz * wz) / denom;       // cot at B
                float rx = ax_ - cx, ry = ay_ - cy, rz = az_ - cz;
                float sx = bx - cx, sy = by - cy, sz2 = bz - cz;
                float cC = (rx * sx + ry * sy + rz * sz2) / denom;      // cot at C
                lx += cC * e1x + cB * e2x;                              // A gets cC*(B-A)+cB*(C-A)
                ly += cC * e1y + cB * e2y;
                lz += cC * e1z + cB * e2z;
            }
        }
        vnx *= sgn; vny *= sgn; vnz *= sgn;
        float nn = sqrtf(vnx * vnx + vny * vny + vnz * vnz) + EPSV;
        if (act) {
            float* fp = feat + (size_t)vi * 9 * NBB + lane;
            fp[0 * NBB] = ax_; fp[1 * NBB] = ay_; fp[2 * NBB] = az_;
            fp[3 * NBB] = vnx / nn; fp[4 * NBB] = vny / nn; fp[5 * NBB] = vnz / nn;
            fp[6 * NBB] = 0.5f * lx; fp[7 * NBB] = 0.5f * ly; fp[8 * NBB] = 0.5f * lz;
        }
    }
}

// ---------------- per-step: layer1  h = relu(feats@W1s + mean_nbr(feats)@W1n + b1) ----------------
__global__ __launch_bounds__(256) void k_layer1(const float* __restrict__ feat,
                                                const int* __restrict__ deg,
                                                const int* __restrict__ nbrB,
                                                const float* __restrict__ W1s,
                                                const float* __restrict__ W1n,
                                                const float* __restrict__ b1,
                                                float* __restrict__ h) {
    // transposed [j][i], row padded 9->12 (48B, 16B-aligned) for ds_read_b128
    __shared__ alignas(16) float sWs[16 * 12];
    __shared__ alignas(16) float sWn[16 * 12];
    __shared__ float sb[16];
    int t = threadIdx.x;
    if (t < 144) {
        int i = t >> 4, j = t & 15;
        sWs[j * 12 + i] = W1s[t];
        sWn[j * 12 + i] = W1n[t];
    }
    if (t < 16) sb[t] = b1[t];
    __syncthreads();
    int g = swiz(blockIdx.x);
    if (g >= GROUPS) return;
    int lane = t & 63;
    int vbase = rfl(g * VPB + (t >> 6) * VPW);
    float own[VPW][9], m[VPW][9];
#pragma unroll
    for (int q = 0; q < VPW; q++) {
        int vi = vbase + q;
        int vil = (vi < NV) ? vi : NV - 1;
        const float* fp = feat + (size_t)vil * 9 * NBB + lane;
#pragma unroll
        for (int i = 0; i < 9; i++) { own[q][i] = fp[i * NBB]; m[q][i] = 0.f; }
        int d = rfl(deg[vil]);
#pragma unroll
        for (int k = 0; k < 6; k++) {
            if (k < d) {
                int u = rfl(nbrB[vil * 6 + k]);
                const float* fu = feat + (size_t)u * 9 * NBB + lane;
#pragma unroll
                for (int i = 0; i < 9; i++) m[q][i] += fu[i * NBB];
            }
        }
        float inv = 1.f / (float)d;
#pragma unroll
        for (int i = 0; i < 9; i++) m[q][i] *= inv;
    }
#pragma unroll
    for (int j = 0; j < 16; j++) {
        const float4* w4s = (const float4*)(sWs + j * 12);
        const float4* w4n = (const float4*)(sWn + j * 12);
        float acc[VPW];
#pragma unroll
        for (int q = 0; q < VPW; q++) acc[q] = sb[j];
#pragma unroll
        for (int p = 0; p < 2; p++) {          // i = 4p..4p+3 via b128
            float4 ws = w4s[p], wn = w4n[p];
#pragma unroll
            for (int q = 0; q < VPW; q++) {
                acc[q] += own[q][4 * p + 0] * ws.x + m[q][4 * p + 0] * wn.x;
                acc[q] += own[q][4 * p + 1] * ws.y + m[q][4 * p + 1] * wn.y;
                acc[q] += own[q][4 * p + 2] * ws.z + m[q][4 * p + 2] * wn.z;
                acc[q] += own[q][4 * p + 3] * ws.w + m[q][4 * p + 3] * wn.w;
            }
        }
        {   // i = 8
            float ws = sWs[j * 12 + 8], wn = sWn[j * 12 + 8];
#pragma unroll
            for (int q = 0; q < VPW; q++) acc[q] += own[q][8] * ws + m[q][8] * wn;
        }
#pragma unroll
        for (int q = 0; q < VPW; q++) {
            int vi = vbase + q;
            if (vi < NV) h[((size_t)vi * 16 + j) * NBB + lane] = fmaxf(acc[q], 0.f);
        }
    }
}

// ---------------- per-step: layer2 + fused head + state update ----------------
// no persistent acc array: each j collapses into dv immediately (R6 spill fix)
__global__ __launch_bounds__(256) void k_layer2(const float* __restrict__ h,
                                                const float* __restrict__ feat,
                                                const int* __restrict__ deg,
                                                const int* __restrict__ nbrB,
                                                const float* __restrict__ W2s,
                                                const float* __restrict__ W2n,
                                                const float* __restrict__ b2,
                                                const float* __restrict__ Wo,
                                                const float* __restrict__ bo,
                                                float* __restrict__ v,
                                                float* __restrict__ sulc) {
    __shared__ alignas(16) float sWs[256];   // transposed [j][i]
    __shared__ alignas(16) float sWn[256];
    __shared__ float sb[16], sWo[48], sbo[3];
    int t = threadIdx.x;
    {
        int i = t >> 4, j = t & 15;
        sWs[j * 16 + i] = W2s[t];
        sWn[j * 16 + i] = W2n[t];
    }
    if (t < 48) { int i = t / 3, c = t - 3 * i; sWo[c * 16 + i] = Wo[t]; }
    if (t < 16) sb[t] = b2[t];
    if (t < 3)  sbo[t] = bo[t];
    __syncthreads();
    int g = swiz(blockIdx.x);
    if (g >= GROUPS) return;
    int lane = t & 63;
    int vbase = rfl(g * VPB + (t >> 6) * VPW);
    float own[VPW][16], m[VPW][16];
    int d0;
#pragma unroll
    for (int q = 0; q < VPW; q++) {
        int vi = vbase + q;
        int vil = (vi < NV) ? vi : NV - 1;
        const float* hp = h + (size_t)vil * 16 * NBB + lane;
#pragma unroll
        for (int i = 0; i < 16; i++) { own[q][i] = hp[i * NBB]; m[q][i] = 0.f; }
        int d = rfl(deg[vil]);
#pragma unroll
        for (int k = 0; k < 6; k++) {
            if (k < d) {
                int u = rfl(nbrB[vil * 6 + k]);
                const float* hu = h + (size_t)u * 16 * NBB + lane;
#pragma unroll
                for (int i = 0; i < 16; i++) m[q][i] += hu[i * NBB];
            }
        }
        float inv = 1.f / (float)d;
#pragma unroll
        for (int i = 0; i < 16; i++) m[q][i] *= inv;
        (void)d0;
    }
    float dv[VPW][3];
#pragma unroll
    for (int q = 0; q < VPW; q++)
#pragma unroll
        for (int c = 0; c < 3; c++) dv[q][c] = sbo[c];
#pragma unroll
    for (int j = 0; j < 16; j++) {
        const float4* w4s = (const float4*)(sWs + j * 16);
        const float4* w4n = (const float4*)(sWn + j * 16);
        float acc[VPW];
#pragma unroll
        for (int q = 0; q < VPW; q++) acc[q] = sb[j];
#pragma unroll
        for (int p = 0; p < 4; p++) {          // i = 4p..4p+3 via b128
            float4 ws = w4s[p], wn = w4n[p];
#pragma unroll
            for (int q = 0; q < VPW; q++) {
                acc[q] += own[q][4 * p + 0] * ws.x + m[q][4 * p + 0] * wn.x;
                acc[q] += own[q][4 * p + 1] * ws.y + m[q][4 * p + 1] * wn.y;
                acc[q] += own[q][4 * p + 2] * ws.z + m[q][4 * p + 2] * wn.z;
                acc[q] += own[q][4 * p + 3] * ws.w + m[q][4 * p + 3] * wn.w;
            }
        }
        float wo0 = sWo[0 * 16 + j], wo1 = sWo[1 * 16 + j], wo2 = sWo[2 * 16 + j];
#pragma unroll
        for (int q = 0; q < VPW; q++) {
            float h2 = fmaxf(acc[q], 0.f);     // fused head: acc never persists past this j
            dv[q][0] += h2 * wo0;
            dv[q][1] += h2 * wo1;
            dv[q][2] += h2 * wo2;
        }
    }
#pragma unroll
    for (int q = 0; q < VPW; q++) {
        int vi = vbase + q;
        if (vi >= NV) break;
        float* vp = v + (size_t)vi * 3 * NBB + lane;
        const float* np_ = feat + ((size_t)vi * 9 + 3) * NBB + lane;  // this step's normals
        vp[0 * NBB] += STEPSZ * dv[q][0];
        vp[1 * NBB] += STEPSZ * dv[q][1];
        vp[2 * NBB] += STEPSZ * dv[q][2];
        sulc[(size_t)vi * NBB + lane] +=
            STEPSZ * (np_[0 * NBB] * dv[q][0] + np_[1 * NBB] * dv[q][1] + np_[2 * NBB] * dv[q][2]);
    }
}

// ---------------- output: (2,B,V,4) = (v*size, sulc) ----------------
__global__ __launch_bounds__(256) void k_out(const float* __restrict__ v,
                                             const float* __restrict__ sulc,
                                             const float* __restrict__ csz,
                                             float4* __restrict__ out) {
    int vi = blockIdx.x * 256 + threadIdx.x;
    int bb = blockIdx.y;
    if (vi >= NV) return;
    float4 o;
    o.x = v[((size_t)vi * 3 + 0) * NBB + bb] * csz[(3 + 0) * NBB + bb];
    o.y = v[((size_t)vi * 3 + 1) * NBB + bb] * csz[(3 + 1) * NBB + bb];
    o.z = v[((size_t)vi * 3 + 2) * NBB + bb] * csz[(3 + 2) * NBB + bb];
    o.w = sulc[(size_t)vi * NBB + bb];
    out[(size_t)bb * NV + vi] = o;
}

extern "C" void kernel_launch(void* const* d_in, const int* in_sizes, int n_in,
                              void* d_out, int out_size, void* d_ws, size_t ws_size,
                              hipStream_t stream) {
    const float* lh  = (const float*)d_in[0];
    const float* rh  = (const float*)d_in[1];
    const float* W1s = (const float*)d_in[2];
    const float* W1n = (const float*)d_in[3];
    const float* b1  = (const float*)d_in[4];
    const float* W2s = (const float*)d_in[5];
    const float* W2n = (const float*)d_in[6];
    const float* b2  = (const float*)d_in[7];
    const float* Wo  = (const float*)d_in[8];
    const float* bo  = (const float*)d_in[9];
    const int* faces = (const int*)d_in[10];

    float* ws   = (float*)d_ws;
    float* v    = ws + OFF_V;
    float* sulc = ws + OFF_SULC;
    float* feat = ws + OFF_FEAT;
    float* h    = ws + OFF_H;
    float* csz  = ws + OFF_CSZ;
    int* ibase  = (int*)(ws + OFF_INT);
    int* deg    = ibase;
    int* nbrB   = ibase + NV;
    int* nbrC   = ibase + NV + NV * 6;

    dim3 gv(NBLK);

    k_zero_deg<<<(NV + 255) / 256, 256, 0, stream>>>(deg);
    k_build<<<(NF + 255) / 256, 256, 0, stream>>>(faces, deg, nbrB, nbrC);
    k_sortring<<<(NV + 255) / 256, 256, 0, stream>>>(deg, nbrB, nbrC);
    k_norm<<<NBB, 256, 0, stream>>>(lh, rh, v, sulc, csz);

    for (int s = 0; s < NSTEPS; s++) {
        k_geom<<<gv, 256, 0, stream>>>(v, deg, nbrB, feat);
        k_layer1<<<gv, 256, 0, stream>>>(feat, deg, nbrB, W1s, W1n, b1, h);
        k_layer2<<<gv, 256, 0, stream>>>(h, feat, deg, nbrB, W2s, W2n, b2, Wo, bo, v, sulc);
    }
    k_out<<<dim3((NV + 255) / 256, NBB), 256, 0, stream>>>(v, sulc, csz, (float4*)d_out);
}